// Round 4
// baseline (174.179 us; speedup 1.0000x reference)
//
#include <hip/hip_runtime.h>

typedef float f32x4 __attribute__((ext_vector_type(4)));
typedef float f32x16 __attribute__((ext_vector_type(16)));
typedef _Float16 f16;
typedef _Float16 f16x2 __attribute__((ext_vector_type(2)));
typedef _Float16 f16x8 __attribute__((ext_vector_type(8)));
typedef unsigned int u32x2 __attribute__((ext_vector_type(2)));
typedef unsigned short u16;
typedef unsigned short u16x4 __attribute__((ext_vector_type(4)));
typedef unsigned int u32;

#define S_LEN 2048
#define NHEAD 16
#define DHEAD 64
#define DMODEL 1024
#define NBATCH 4

__device__ __forceinline__ void gload16(const u16* g, const uint4* l) {
  __builtin_amdgcn_global_load_lds((const __attribute__((address_space(1))) void*)g,
                                   (__attribute__((address_space(3))) void*)l, 16, 0, 0);
}

// exp path: whole chain builtin-visible (exp2f -> cvt_pkrtz -> MFMA). Raw v_exp_f32
// or builtin-exp2 feeding inline-ASM consumers corrupts (TRANS dest hazard invisible
// across asm boundaries; r7/r9). Do not reintroduce asm into this chain.
// R3 lesson: replacing the accL MFMA with fdot2 on the same fragment words failed
// correctness despite layout-invariant pairing math -- this chain's consumer set is
// codegen-fragile. accL stays on the MFMA path.

// ---------------- convert x (f32 -> f16), packed ----------------
__global__ void cvt_x(const float* __restrict__ x, u16* __restrict__ o, int n4) {
  int i = blockIdx.x * blockDim.x + threadIdx.x;
  int st = gridDim.x * blockDim.x;
  for (; i < n4; i += st) {
    float4 v = reinterpret_cast<const float4*>(x)[i];
    uint2 r;
    r.x = __builtin_bit_cast(u32, __builtin_amdgcn_cvt_pkrtz(v.x, v.y));
    r.y = __builtin_bit_cast(u32, __builtin_amdgcn_cvt_pkrtz(v.z, v.w));
    reinterpret_cast<uint2*>(o)[i] = r;
  }
}

// ---------------- transpose W: f32 [K][N] -> f16 [N][K] ----------------
__global__ void trans_w(const float* __restrict__ W, u16* __restrict__ wt) {
  __shared__ float t[32][33];
  int bx = blockIdx.x * 32, by = blockIdx.y * 32;
  int tx = threadIdx.x & 31, ty = threadIdx.x >> 5;  // ty in 0..7
#pragma unroll
  for (int i = 0; i < 32; i += 8)
    t[ty + i][tx] = W[(size_t)(by + ty + i) * DMODEL + bx + tx];
  __syncthreads();
#pragma unroll
  for (int i = 0; i < 32; i += 8)
    wt[(size_t)(bx + ty + i) * DMODEL + by + tx] = __builtin_bit_cast(u16, (f16)t[tx][ty + i]);
}

// ---------------- fused QKV projection GEMM ----------------
// Round-0 envelope (proven): 128x128 tile, BK=32, 4 waves, 48KB LDS, 3 blocks/CU,
// grid (64,24)=1536 blocks -> exactly 2 full scheduling rounds.
// 32x32x16 MFMA engine, acc[2][2] f32x16 (64 AGPR), 8 ds_read_b128/iter.
// 3-buf counted-vmcnt pipeline: {vmcnt(4) -> barrier -> stage(it+2) -> ds_read
// -> 8 MFMA}. Stage staying in flight across the barrier (T4).
__global__ __launch_bounds__(256) void qkv_gemm(
    const u16* __restrict__ A, const u16* __restrict__ Wt,
    const float* __restrict__ bq, const float* __restrict__ bk, const float* __restrict__ bv,
    const float* __restrict__ mask,
    u16* __restrict__ Qo, u16* __restrict__ Ko, u16* __restrict__ Vo)
{
  __shared__ uint4 As4[3][512];   // [128 rows][4 slots] per buffer
  __shared__ uint4 Bs4[3][512];
  const int tid = threadIdx.x;
  const int lane = tid & 63;
  const int wid = tid >> 6;
  const int l31 = lane & 31, hi = lane >> 5;
  const int m0 = blockIdx.x * 128;
  const int n0 = blockIdx.y * 128;
  const int wr = (wid >> 1) * 64, wc = (wid & 1) * 64;

  f32x16 acc[2][2] = {};

  // glds geometry: wave w stages phys chunks w*64+lane, +256.
  // phys chunk c = row*4 + p; stored data = logical slot l = p ^ ((row>>1)&3).
  const int c0 = wid * 64 + lane, c1 = c0 + 256;
  const int r0 = c0 >> 2, r1 = c1 >> 2;
  const int p4 = lane & 3;
  const int sl0 = p4 ^ ((r0 >> 1) & 3);
  const int sl1 = p4 ^ ((r1 >> 1) & 3);
  const u16* ag0 = A  + (size_t)(m0 + r0) * 1024 + sl0 * 8;
  const u16* ag1 = A  + (size_t)(m0 + r1) * 1024 + sl1 * 8;
  const u16* bg0 = Wt + (size_t)(n0 + r0) * 1024 + sl0 * 8;
  const u16* bg1 = Wt + (size_t)(n0 + r1) * 1024 + sl1 * 8;

  auto stage = [&](int buf, int kt) {
    gload16(ag0 + kt, &As4[buf][wid * 64]);
    gload16(ag1 + kt, &As4[buf][wid * 64 + 256]);
    gload16(bg0 + kt, &Bs4[buf][wid * 64]);
    gload16(bg1 + kt, &Bs4[buf][wid * 64 + 256]);
  };

  // iteration-invariant LDS read offsets (u16 units)
  int aoff[2][2], boff[2][2];
#pragma unroll
  for (int mi = 0; mi < 2; mi++) {
    int r = wr + mi * 32 + l31;
#pragma unroll
    for (int ks = 0; ks < 2; ks++)
      aoff[mi][ks] = r * 32 + (((ks * 2 + hi) ^ ((r >> 1) & 3)) * 8);
  }
#pragma unroll
  for (int ni = 0; ni < 2; ni++) {
    int r = wc + ni * 32 + l31;
#pragma unroll
    for (int ks = 0; ks < 2; ks++)
      boff[ni][ks] = r * 32 + (((ks * 2 + hi) ^ ((r >> 1) & 3)) * 8);
  }

  stage(0, 0);
  stage(1, 32);
  __syncthreads();              // one-time full drain: buf0+buf1 resident

  const int NT = 1024 / 32;
  for (int it = 0; it < NT; ++it) {
    if (it + 1 < NT) asm volatile("s_waitcnt vmcnt(4)" ::: "memory");
    else             asm volatile("s_waitcnt vmcnt(0)" ::: "memory");
    __builtin_amdgcn_s_barrier();
    __builtin_amdgcn_sched_barrier(0);
    const int cur = it % 3;
    if (it + 2 < NT) stage((it + 2) % 3, (it + 2) * 32);   // stays in flight past barrier

    const u16* As = (const u16*)&As4[cur][0];
    const u16* Bs = (const u16*)&Bs4[cur][0];
    f16x8 af[2][2], bf[2][2];
#pragma unroll
    for (int mi = 0; mi < 2; mi++)
#pragma unroll
      for (int ks = 0; ks < 2; ks++)
        af[mi][ks] = *(const f16x8*)&As[aoff[mi][ks]];
#pragma unroll
    for (int ni = 0; ni < 2; ni++)
#pragma unroll
      for (int ks = 0; ks < 2; ks++)
        bf[ni][ks] = *(const f16x8*)&Bs[boff[ni][ks]];

#pragma unroll
    for (int ks = 0; ks < 2; ks++)
#pragma unroll
      for (int mi = 0; mi < 2; mi++)
#pragma unroll
        for (int ni = 0; ni < 2; ni++)
          acc[mi][ni] = __builtin_amdgcn_mfma_f32_32x32x16_f16(af[mi][ks], bf[ni][ks], acc[mi][ni], 0, 0, 0);
  }

  // ---- epilogue: scatter into Q/K/V layouts ----
  const int sel = n0 >> 10;                    // 0:Q 1:K 2:V
  const float* bias = (sel == 0) ? bq : (sel == 1) ? bk : bv;
  const int nbase = (n0 & 1023) + wc;
  const float QSCALE = 0.18033688011112042f;   // log2(e)/8  (exp2-domain softmax)
#pragma unroll
  for (int mi = 0; mi < 2; mi++)
#pragma unroll
    for (int ni = 0; ni < 2; ni++) {
      const int ncol = nbase + ni * 32 + l31;
      const float bi = bias[ncol];
      const int h = ncol >> 6, dh = ncol & 63;
#pragma unroll
      for (int r4 = 0; r4 < 4; r4++) {
        // C layout (32x32): col = lane&31, row = (reg&3) + 8*(reg>>2) + 4*(lane>>5)
        const int rowb = m0 + wr + mi * 32 + 8 * r4 + 4 * hi;
        const int bb = rowb >> 11, s0 = rowb & 2047;
        const size_t bh = (size_t)(bb * NHEAD + h);
        if (sel == 0) {
#pragma unroll
          for (int j = 0; j < 4; j++)
            Qo[(bh * S_LEN + s0 + j) * DHEAD + dh] =
                __builtin_bit_cast(u16, (f16)((acc[mi][ni][r4 * 4 + j] + bi) * QSCALE));
        } else if (sel == 1) {
#pragma unroll
          for (int j = 0; j < 4; j++)
            Ko[(bh * S_LEN + s0 + j) * DHEAD + dh] =
                __builtin_bit_cast(u16, (f16)(acc[mi][ni][r4 * 4 + j] + bi));
        } else {
          const float4 mk = *(const float4*)&mask[bb * S_LEN + s0];   // s0 % 4 == 0
          u16x4 pk;
#pragma unroll
          for (int j = 0; j < 4; j++) {
            float v = acc[mi][ni][r4 * 4 + j] + bi;
            float mj = (j == 0) ? mk.x : (j == 1) ? mk.y : (j == 2) ? mk.z : mk.w;
            if (mj <= 0.f) v = 0.f;            // fold mask into V
            pk[j] = __builtin_bit_cast(u16, (f16)v);
          }
          *(u16x4*)&Vo[(bh * DHEAD + dh) * S_LEN + s0] = pk;  // 4 consecutive s -> 8B store
        }
      }
    }
}

// ---------------- flash attention: swapped-QK^T 32x32 f16, static-max ----------------
// ROUND 4: occupancy doubled. Round-2 was grid-limited (512 blocks = 2/CU, Occ 18%,
// MfmaUtil 43 + VALU 39 with ~18% stall). Each wave now owns ONE 32-row q-subtile
// (was two), qt split 8 -> 16, grid 1024 = 4 blocks/CU = 16 waves/CU. LDS cut
// 53 -> 36KB via 2-buf double-buffer; schedule becomes T3-minimal: stage(it+1)
// issued right after the barrier, drained by vmcnt(0) at the NEXT gate, so the
// load flies under the whole MFMA phase. Math per q-row identical to round 2
// (accL MFMA denominator, accLA-based epilogue -- proven path, see R3 lesson).
__global__ __launch_bounds__(256, 4) void attn(
    const u16* __restrict__ Q, const u16* __restrict__ K, const u16* __restrict__ Vt,
    const float* __restrict__ mask, float* __restrict__ out)
{
  __shared__ uint4 Ks4[2][512];                // [t=64][slot=8] skewed 16B chunks
  __shared__ uint4 Vs4[2][512];                // [d=64][slot=8] skewed (V^T)
  __shared__ __align__(16) u16 MsAll[S_LEN];   // whole mask row as f16
  const int tid = threadIdx.x;
  const int lane = tid & 63, wid = tid >> 6;
  const int l31 = lane & 31, hi = lane >> 5;
  const int sid = blockIdx.x;                  // grid 1024
  const int qt = (sid >> 3) & 15;
  const int bh = (sid & 7) + 8 * (sid >> 7);
  const int b = bh >> 4, h = bh & 15;
  const size_t base = (size_t)bh * S_LEN * DHEAD;
  const u16* Qp = Q + base;
  const u16* Kp = K + base;
  const u16* Vp = Vt + base;                   // [d][s]
  const float* mp = mask + b * S_LEN;
  const int q0 = qt * 128 + wid * 32;          // wave owns 32 q-rows

  // Q as B-fragments (single subtile)
  f16x8 aqA[4];
#pragma unroll
  for (int kc = 0; kc < 4; kc++)
    aqA[kc] = *(const f16x8*)&Qp[(size_t)(q0 + l31) * DHEAD + kc * 16 + hi * 8];

  f32x16 accO0A = {}, accO1A = {}, accLA = {};

  // staging geometry (G21: linear LDS dest, inverse-skewed global source)
  const int cA_ = wid * 128 + lane, cB_ = cA_ + 64;
  const int rk0 = cA_ >> 3, rk1 = cB_ >> 3;
  const int p8 = lane & 7;
  const int cc0 = (p8 - ((rk0 + (rk0 >> 3)) & 7)) & 7;
  const int cc1 = (p8 - ((rk1 + (rk1 >> 3)) & 7)) & 7;
  const u16* kg0 = Kp + (size_t)rk0 * DHEAD + cc0 * 8;
  const u16* kg1 = Kp + (size_t)rk1 * DHEAD + cc1 * 8;
  const u16* vg0 = Vp + (size_t)rk0 * S_LEN + cc0 * 8;
  const u16* vg1 = Vp + (size_t)rk1 * S_LEN + cc1 * 8;

  auto stage = [&](int buf) {
    gload16(kg0, &Ks4[buf][wid * 128]); gload16(kg1, &Ks4[buf][wid * 128 + 64]);
    gload16(vg0, &Vs4[buf][wid * 128]); gload16(vg1, &Vs4[buf][wid * 128 + 64]);
    kg0 += 64 * DHEAD; kg1 += 64 * DHEAD; vg0 += 64; vg1 += 64;
  };

  // LDS read slot table (shared by K's kc-loop and V's g-loop)
  const int swA = (l31 + (l31 >> 3)) & 7;
  const int swB = (swA + 4) & 7;
  int idxA[4], idxB[4];
#pragma unroll
  for (int kc = 0; kc < 4; kc++) {
    idxA[kc] = l31 * 8 + ((kc * 2 + hi + swA) & 7);
    idxB[kc] = (32 + l31) * 8 + ((kc * 2 + hi + swB) & 7);
  }

  // one-time mask preload (f32 -> f16, 8 values/thread)
  {
    float4 ml0 = *(const float4*)&mp[tid * 8];
    float4 ml1 = *(const float4*)&mp[tid * 8 + 4];
    uint4 w;
    w.x = __builtin_bit_cast(u32, __builtin_amdgcn_cvt_pkrtz(ml0.x, ml0.y));
    w.y = __builtin_bit_cast(u32, __builtin_amdgcn_cvt_pkrtz(ml0.z, ml0.w));
    w.z = __builtin_bit_cast(u32, __builtin_amdgcn_cvt_pkrtz(ml1.x, ml1.y));
    w.w = __builtin_bit_cast(u32, __builtin_amdgcn_cvt_pkrtz(ml1.z, ml1.w));
    *(uint4*)&MsAll[tid * 8] = w;
  }
  stage(0);
  __syncthreads();              // full drain: buf0 + MsAll resident

  const int NT = S_LEN / 64;
  for (int it = 0; it < NT; ++it) {
    asm volatile("s_waitcnt vmcnt(0)" ::: "memory");   // stage(it) landed
    __builtin_amdgcn_s_barrier();                      // all waves done reading buf it-1
    __builtin_amdgcn_sched_barrier(0);
    const int cur = it & 1;
    const uint4* ks = &Ks4[cur][0];
    const uint4* vs = &Vs4[cur][0];
    if (it + 1 < NT) stage((it + 1) & 1);   // overwrites buf read at it-1; flies under MFMA

    // ---- S^T = K Q^T (t=0..31 in sA0, t=32..63 in sA1) ----
    f32x16 sA0 = {}, sA1 = {};
    __builtin_amdgcn_s_setprio(1);
#pragma unroll
    for (int kc = 0; kc < 4; kc++) {
      f16x8 k0 = *(const f16x8*)&ks[idxA[kc]];
      f16x8 k1 = *(const f16x8*)&ks[idxB[kc]];
      sA0 = __builtin_amdgcn_mfma_f32_32x32x16_f16(k0, aqA[kc], sA0, 0, 0, 0);
      sA1 = __builtin_amdgcn_mfma_f32_32x32x16_f16(k1, aqA[kc], sA1, 0, 0, 0);
    }
    __builtin_amdgcn_s_setprio(0);

    // ---- fused p=exp2(S) -> f16 pack (pkrtz) -> permlane -> PV, per 16-t group ----
#pragma unroll
    for (int g = 0; g < 4; g++) {
      const f32x16& srcA = (g < 2) ? sA0 : sA1;
      const int o = (g & 1) * 8;
      u32 wa[4];
#pragma unroll
      for (int s = 0; s < 4; s++) {
        wa[s] = __builtin_bit_cast(u32, __builtin_amdgcn_cvt_pkrtz(
                    __builtin_amdgcn_exp2f(srcA[o + 2 * s]),
                    __builtin_amdgcn_exp2f(srcA[o + 2 * s + 1])));
      }
      u32x2 rA0 = __builtin_amdgcn_permlane32_swap(wa[0], wa[2], false, false);
      u32x2 rA1 = __builtin_amdgcn_permlane32_swap(wa[1], wa[3], false, false);
      uint4 f4A; f4A.x = rA0[0]; f4A.y = rA1[0]; f4A.z = rA0[1]; f4A.w = rA1[1];
      f16x8 fA = __builtin_bit_cast(f16x8, f4A);
      f16x8 bv0 = *(const f16x8*)&vs[idxA[g]];
      f16x8 bv1 = *(const f16x8*)&vs[idxB[g]];
      f16x8 bm = *(const f16x8*)&MsAll[it * 64 + g * 16 + hi * 8];
      __builtin_amdgcn_s_setprio(1);
      accO0A = __builtin_amdgcn_mfma_f32_32x32x16_f16(fA, bv0, accO0A, 0, 0, 0);
      accO1A = __builtin_amdgcn_mfma_f32_32x32x16_f16(fA, bv1, accO1A, 0, 0, 0);
      accLA  = __builtin_amdgcn_mfma_f32_32x32x16_f16(fA, bm,  accLA,  0, 0, 0);
      __builtin_amdgcn_s_setprio(0);
    }
  }

  // ---- epilogue (round-2 proven form) ----
#pragma unroll
  for (int r = 0; r < 16; r++) {
    int qr = (r & 3) + 8 * (r >> 2) + 4 * hi;
    float lA = accLA[r];
    float iA = (lA > 0.f) ? 1.f / lA : 0.f;
    float* opA = out + ((size_t)(b * S_LEN + q0 + qr) * DMODEL) + h * DHEAD;
    opA[l31] = accO0A[r] * iA;
    opA[32 + l31] = accO1A[r] * iA;
  }
}

extern "C" void kernel_launch(void* const* d_in, const int* in_sizes, int n_in,
                              void* d_out, int out_size, void* d_ws, size_t ws_size,
                              hipStream_t stream) {
  const float* x    = (const float*)d_in[0];
  const float* mask = (const float*)d_in[1];
  const float* Wq   = (const float*)d_in[2];
  const float* bq   = (const float*)d_in[3];
  const float* Wk   = (const float*)d_in[4];
  const float* bk   = (const float*)d_in[5];
  const float* Wv   = (const float*)d_in[6];
  const float* bv   = (const float*)d_in[7];
  float* out = (float*)d_out;

  u16* xb = (u16*)d_ws;                         // [8192][1024] f16
  u16* wt = xb + (size_t)8192 * 1024;           // [3072][1024] f16 (W^T, q|k|v)
  u16* Qb = wt + (size_t)3072 * 1024;           // [4][16][2048][64]
  u16* Kb = Qb + (size_t)8388608;               // [4][16][2048][64]
  u16* Vb = Kb + (size_t)8388608;               // [4][16][64][2048] (mask-zeroed)

  cvt_x<<<2048, 256, 0, stream>>>(x, xb, (8192 * 1024) / 4);
  trans_w<<<dim3(32, 32), 256, 0, stream>>>(Wq, wt);
  trans_w<<<dim3(32, 32), 256, 0, stream>>>(Wk, wt + (size_t)1024 * 1024);
  trans_w<<<dim3(32, 32), 256, 0, stream>>>(Wv, wt + (size_t)2 * 1024 * 1024);
  qkv_gemm<<<dim3(64, 24), 256, 0, stream>>>(xb, wt, bq, bk, bv, mask, Qb, Kb, Vb);
  attn<<<1024, 256, 0, stream>>>(Qb, Kb, Vb, mask, out);
}

// Round 6
// 167.543 us; speedup vs baseline: 1.0396x; 1.0396x over previous
//
#include <hip/hip_runtime.h>

typedef float f32x4 __attribute__((ext_vector_type(4)));
typedef float f32x16 __attribute__((ext_vector_type(16)));
typedef _Float16 f16;
typedef _Float16 f16x2 __attribute__((ext_vector_type(2)));
typedef _Float16 f16x8 __attribute__((ext_vector_type(8)));
typedef unsigned int u32x2 __attribute__((ext_vector_type(2)));
typedef unsigned short u16;
typedef unsigned short u16x4 __attribute__((ext_vector_type(4)));
typedef unsigned int u32;

#define S_LEN 2048
#define NHEAD 16
#define DHEAD 64
#define DMODEL 1024
#define NBATCH 4

__device__ __forceinline__ void gload16(const u16* g, const uint4* l) {
  __builtin_amdgcn_global_load_lds((const __attribute__((address_space(1))) void*)g,
                                   (__attribute__((address_space(3))) void*)l, 16, 0, 0);
}

// exp path: whole chain builtin-visible (exp2f -> cvt_pkrtz -> MFMA). Raw v_exp_f32
// or builtin-exp2 feeding inline-ASM consumers corrupts (r7/r9).
// R3/R5 ROOT CAUSE (found R6): permlane32_swap(x, x) with the SAME register for both
// operands degenerates (it's a two-destination swap: vdst.hi <-> vsrc.lo; with one
// register the pair returns 2x partner, not self+partner). Merge partner halves with
// __shfl_xor instead. NEVER pass the same VGPR to both permlane32_swap operands.

// ---------------- convert x (f32 -> f16), packed ----------------
__global__ void cvt_x(const float* __restrict__ x, u16* __restrict__ o, int n4) {
  int i = blockIdx.x * blockDim.x + threadIdx.x;
  int st = gridDim.x * blockDim.x;
  for (; i < n4; i += st) {
    float4 v = reinterpret_cast<const float4*>(x)[i];
    uint2 r;
    r.x = __builtin_bit_cast(u32, __builtin_amdgcn_cvt_pkrtz(v.x, v.y));
    r.y = __builtin_bit_cast(u32, __builtin_amdgcn_cvt_pkrtz(v.z, v.w));
    reinterpret_cast<uint2*>(o)[i] = r;
  }
}

// ---------------- transpose W: f32 [K][N] -> f16 [N][K] ----------------
__global__ void trans_w(const float* __restrict__ W, u16* __restrict__ wt) {
  __shared__ float t[32][33];
  int bx = blockIdx.x * 32, by = blockIdx.y * 32;
  int tx = threadIdx.x & 31, ty = threadIdx.x >> 5;  // ty in 0..7
#pragma unroll
  for (int i = 0; i < 32; i += 8)
    t[ty + i][tx] = W[(size_t)(by + ty + i) * DMODEL + bx + tx];
  __syncthreads();
#pragma unroll
  for (int i = 0; i < 32; i += 8)
    wt[(size_t)(bx + ty + i) * DMODEL + by + tx] = __builtin_bit_cast(u16, (f16)t[tx][ty + i]);
}

// ---------------- fused QKV projection GEMM ----------------
// Round-0 envelope (proven): 128x128 tile, BK=32, 4 waves, 48KB LDS, 3 blocks/CU,
// grid (64,24)=1536 blocks -> exactly 2 full scheduling rounds.
// 32x32x16 MFMA engine, acc[2][2] f32x16 (64 AGPR), 8 ds_read_b128/iter.
// 3-buf counted-vmcnt pipeline: {vmcnt(4) -> barrier -> stage(it+2) -> ds_read
// -> 8 MFMA}. Stage staying in flight across the barrier (T4).
__global__ __launch_bounds__(256) void qkv_gemm(
    const u16* __restrict__ A, const u16* __restrict__ Wt,
    const float* __restrict__ bq, const float* __restrict__ bk, const float* __restrict__ bv,
    const float* __restrict__ mask,
    u16* __restrict__ Qo, u16* __restrict__ Ko, u16* __restrict__ Vo)
{
  __shared__ uint4 As4[3][512];   // [128 rows][4 slots] per buffer
  __shared__ uint4 Bs4[3][512];
  const int tid = threadIdx.x;
  const int lane = tid & 63;
  const int wid = tid >> 6;
  const int l31 = lane & 31, hi = lane >> 5;
  const int m0 = blockIdx.x * 128;
  const int n0 = blockIdx.y * 128;
  const int wr = (wid >> 1) * 64, wc = (wid & 1) * 64;

  f32x16 acc[2][2] = {};

  // glds geometry: wave w stages phys chunks w*64+lane, +256.
  // phys chunk c = row*4 + p; stored data = logical slot l = p ^ ((row>>1)&3).
  const int c0 = wid * 64 + lane, c1 = c0 + 256;
  const int r0 = c0 >> 2, r1 = c1 >> 2;
  const int p4 = lane & 3;
  const int sl0 = p4 ^ ((r0 >> 1) & 3);
  const int sl1 = p4 ^ ((r1 >> 1) & 3);
  const u16* ag0 = A  + (size_t)(m0 + r0) * 1024 + sl0 * 8;
  const u16* ag1 = A  + (size_t)(m0 + r1) * 1024 + sl1 * 8;
  const u16* bg0 = Wt + (size_t)(n0 + r0) * 1024 + sl0 * 8;
  const u16* bg1 = Wt + (size_t)(n0 + r1) * 1024 + sl1 * 8;

  auto stage = [&](int buf, int kt) {
    gload16(ag0 + kt, &As4[buf][wid * 64]);
    gload16(ag1 + kt, &As4[buf][wid * 64 + 256]);
    gload16(bg0 + kt, &Bs4[buf][wid * 64]);
    gload16(bg1 + kt, &Bs4[buf][wid * 64 + 256]);
  };

  // iteration-invariant LDS read offsets (u16 units)
  int aoff[2][2], boff[2][2];
#pragma unroll
  for (int mi = 0; mi < 2; mi++) {
    int r = wr + mi * 32 + l31;
#pragma unroll
    for (int ks = 0; ks < 2; ks++)
      aoff[mi][ks] = r * 32 + (((ks * 2 + hi) ^ ((r >> 1) & 3)) * 8);
  }
#pragma unroll
  for (int ni = 0; ni < 2; ni++) {
    int r = wc + ni * 32 + l31;
#pragma unroll
    for (int ks = 0; ks < 2; ks++)
      boff[ni][ks] = r * 32 + (((ks * 2 + hi) ^ ((r >> 1) & 3)) * 8);
  }

  stage(0, 0);
  stage(1, 32);
  __syncthreads();              // one-time full drain: buf0+buf1 resident

  const int NT = 1024 / 32;
  for (int it = 0; it < NT; ++it) {
    if (it + 1 < NT) asm volatile("s_waitcnt vmcnt(4)" ::: "memory");
    else             asm volatile("s_waitcnt vmcnt(0)" ::: "memory");
    __builtin_amdgcn_s_barrier();
    __builtin_amdgcn_sched_barrier(0);
    const int cur = it % 3;
    if (it + 2 < NT) stage((it + 2) % 3, (it + 2) * 32);   // stays in flight past barrier

    const u16* As = (const u16*)&As4[cur][0];
    const u16* Bs = (const u16*)&Bs4[cur][0];
    f16x8 af[2][2], bf[2][2];
#pragma unroll
    for (int mi = 0; mi < 2; mi++)
#pragma unroll
      for (int ks = 0; ks < 2; ks++)
        af[mi][ks] = *(const f16x8*)&As[aoff[mi][ks]];
#pragma unroll
    for (int ni = 0; ni < 2; ni++)
#pragma unroll
      for (int ks = 0; ks < 2; ks++)
        bf[ni][ks] = *(const f16x8*)&Bs[boff[ni][ks]];

#pragma unroll
    for (int ks = 0; ks < 2; ks++)
#pragma unroll
      for (int mi = 0; mi < 2; mi++)
#pragma unroll
        for (int ni = 0; ni < 2; ni++)
          acc[mi][ni] = __builtin_amdgcn_mfma_f32_32x32x16_f16(af[mi][ks], bf[ni][ks], acc[mi][ni], 0, 0, 0);
  }

  // ---- epilogue: scatter into Q/K/V layouts ----
  const int sel = n0 >> 10;                    // 0:Q 1:K 2:V
  const float* bias = (sel == 0) ? bq : (sel == 1) ? bk : bv;
  const int nbase = (n0 & 1023) + wc;
  const float QSCALE = 0.18033688011112042f;   // log2(e)/8  (exp2-domain softmax)
#pragma unroll
  for (int mi = 0; mi < 2; mi++)
#pragma unroll
    for (int ni = 0; ni < 2; ni++) {
      const int ncol = nbase + ni * 32 + l31;
      const float bi = bias[ncol];
      const int h = ncol >> 6, dh = ncol & 63;
#pragma unroll
      for (int r4 = 0; r4 < 4; r4++) {
        // C layout (32x32): col = lane&31, row = (reg&3) + 8*(reg>>2) + 4*(lane>>5)
        const int rowb = m0 + wr + mi * 32 + 8 * r4 + 4 * hi;
        const int bb = rowb >> 11, s0 = rowb & 2047;
        const size_t bh = (size_t)(bb * NHEAD + h);
        if (sel == 0) {
#pragma unroll
          for (int j = 0; j < 4; j++)
            Qo[(bh * S_LEN + s0 + j) * DHEAD + dh] =
                __builtin_bit_cast(u16, (f16)((acc[mi][ni][r4 * 4 + j] + bi) * QSCALE));
        } else if (sel == 1) {
#pragma unroll
          for (int j = 0; j < 4; j++)
            Ko[(bh * S_LEN + s0 + j) * DHEAD + dh] =
                __builtin_bit_cast(u16, (f16)(acc[mi][ni][r4 * 4 + j] + bi));
        } else {
          const float4 mk = *(const float4*)&mask[bb * S_LEN + s0];   // s0 % 4 == 0
          u16x4 pk;
#pragma unroll
          for (int j = 0; j < 4; j++) {
            float v = acc[mi][ni][r4 * 4 + j] + bi;
            float mj = (j == 0) ? mk.x : (j == 1) ? mk.y : (j == 2) ? mk.z : mk.w;
            if (mj <= 0.f) v = 0.f;            // fold mask into V
            pk[j] = __builtin_bit_cast(u16, (f16)v);
          }
          *(u16x4*)&Vo[(bh * DHEAD + dh) * S_LEN + s0] = pk;  // 4 consecutive s -> 8B store
        }
      }
    }
}

// ---------------- flash attention: swapped-QK^T 32x32 f16, static-max, pipelined ----------------
// grid 512; 4 waves/block, wave owns q rows q0..q0+63 (two 32-subtiles) -- round-2 base
// (best LDS economy: 8 waves/CU x full K-frag reuse).
// ROUND 6 (= R5 + the permlane fix): accL MFMAs removed (-8/40 per iter):
//  * mask folded into QK^T C-INIT: Mbias LDS table (f32, C-layout-permuted) holds
//    0 / -1e5 per t; sA/sB start from it -> p = exp2(S-1e5) == 0.0f exactly for
//    masked t. accO unaffected (V already mask-zeroed).
//  * denominator l(q) = sum_t p accumulated as PLAIN f32 adds on the raw exp2
//    outputs (pre-pack). Lane covers its 32-of-64 t-subset; partner (lane^32)
//    holds the complement; merged via __shfl_xor (NOT same-reg permlane swap).
//  * 1/l moved from lane-space (q=l31) to reg-space (q=qr) via ds_bpermute.
__global__ __launch_bounds__(256, 2) void attn(
    const u16* __restrict__ Q, const u16* __restrict__ K, const u16* __restrict__ Vt,
    const float* __restrict__ mask, float* __restrict__ out)
{
  __shared__ uint4 Ks4[3][512];                // [t=64][slot=8] skewed 16B chunks
  __shared__ uint4 Vs4[3][512];                // [d=64][slot=8] skewed (V^T)
  __shared__ float Mbias[S_LEN];               // mask bias, C-layout-permuted (8KB)
  const int tid = threadIdx.x;
  const int lane = tid & 63, wid = tid >> 6;
  const int l31 = lane & 31, hi = lane >> 5;
  const int sid = blockIdx.x;
  const int qt = (sid >> 3) & 7;
  const int bh = (sid & 7) + 8 * (sid >> 6);
  const int b = bh >> 4, h = bh & 15;
  const size_t base = (size_t)bh * S_LEN * DHEAD;
  const u16* Qp = Q + base;
  const u16* Kp = K + base;
  const u16* Vp = Vt + base;                   // [d][s]
  const float* mp = mask + b * S_LEN;
  const int q0 = qt * 256 + wid * 64;

  // Q as B-fragments for the two 32-row subtiles
  f16x8 aqA[4], aqB[4];
#pragma unroll
  for (int kc = 0; kc < 4; kc++) {
    aqA[kc] = *(const f16x8*)&Qp[(size_t)(q0 + l31) * DHEAD + kc * 16 + hi * 8];
    aqB[kc] = *(const f16x8*)&Qp[(size_t)(q0 + 32 + l31) * DHEAD + kc * 16 + hi * 8];
  }

  f32x16 accO0A = {}, accO1A = {};
  f32x16 accO0B = {}, accO1B = {};
  float lA = 0.f, lB = 0.f;                    // denominator partials (own t-subset)

  // staging geometry (G21: linear LDS dest, inverse-skewed global source)
  const int cA_ = wid * 128 + lane, cB_ = cA_ + 64;
  const int rk0 = cA_ >> 3, rk1 = cB_ >> 3;
  const int p8 = lane & 7;
  const int cc0 = (p8 - ((rk0 + (rk0 >> 3)) & 7)) & 7;
  const int cc1 = (p8 - ((rk1 + (rk1 >> 3)) & 7)) & 7;
  const u16* kg0 = Kp + (size_t)rk0 * DHEAD + cc0 * 8;
  const u16* kg1 = Kp + (size_t)rk1 * DHEAD + cc1 * 8;
  const u16* vg0 = Vp + (size_t)rk0 * S_LEN + cc0 * 8;
  const u16* vg1 = Vp + (size_t)rk1 * S_LEN + cc1 * 8;

  auto stage = [&](int buf) {
    gload16(kg0, &Ks4[buf][wid * 128]); gload16(kg1, &Ks4[buf][wid * 128 + 64]);
    gload16(vg0, &Vs4[buf][wid * 128]); gload16(vg1, &Vs4[buf][wid * 128 + 64]);
    kg0 += 64 * DHEAD; kg1 += 64 * DHEAD; vg0 += 64; vg1 += 64;
  };

  // LDS read slot table (shared by K's kc-loop and V's g-loop)
  const int swA = (l31 + (l31 >> 3)) & 7;
  const int swB = (swA + 4) & 7;
  int idxA[4], idxB[4];
#pragma unroll
  for (int kc = 0; kc < 4; kc++) {
    idxA[kc] = l31 * 8 + ((kc * 2 + hi + swA) & 7);
    idxB[kc] = (32 + l31) * 8 + ((kc * 2 + hi + swB) & 7);
  }

  // one-time mask-bias preload, scattered into C-layout order:
  // perm(t) = (t>>6)*64 + sub*32 + hi*16 + r, where w=t&31, sub=(t>>5)&1,
  // hi=(w>>2)&1, r=(w&3)+4*(w>>3)  (inverse of row w = (r&3)+8*(r>>2)+4*hi)
  {
    float4 ml0 = *(const float4*)&mp[tid * 8];
    float4 ml1 = *(const float4*)&mp[tid * 8 + 4];
    float mv[8] = {ml0.x, ml0.y, ml0.z, ml0.w, ml1.x, ml1.y, ml1.z, ml1.w};
#pragma unroll
    for (int j = 0; j < 8; j++) {
      int t = tid * 8 + j;
      int w = t & 31, sub = (t >> 5) & 1;
      int hi_ = (w >> 2) & 1, r_ = (w & 3) + 4 * (w >> 3);
      Mbias[(t >> 6) * 64 + sub * 32 + hi_ * 16 + r_] = (mv[j] > 0.f) ? 0.f : -1.0e5f;
    }
  }
  stage(0);
  stage(1);
  __syncthreads();              // one-time full drain: buf0+buf1+Mbias resident

  const int NT = S_LEN / 64;
  for (int it = 0; it < NT; ++it) {
    if (it + 1 < NT) asm volatile("s_waitcnt vmcnt(4)" ::: "memory");
    else             asm volatile("s_waitcnt vmcnt(0)" ::: "memory");
    __builtin_amdgcn_s_barrier();
    __builtin_amdgcn_sched_barrier(0);
    const int cur = it % 3;
    const uint4* ks = &Ks4[cur][0];
    const uint4* vs = &Vs4[cur][0];
    if (it + 2 < NT) stage((it + 2) % 3);      // stays in flight past barrier

    // ---- C-init from mask bias (broadcast reads; sub0 for sA0/sB0, sub1 for sA1/sB1) ----
    f32x16 ini0, ini1;
    {
      const f32x4* b0 = (const f32x4*)&Mbias[it * 64 + hi * 16];
      const f32x4* b1 = (const f32x4*)&Mbias[it * 64 + 32 + hi * 16];
#pragma unroll
      for (int c = 0; c < 4; c++) {
        f32x4 v0 = b0[c], v1 = b1[c];
#pragma unroll
        for (int j = 0; j < 4; j++) { ini0[c * 4 + j] = v0[j]; ini1[c * 4 + j] = v1[j]; }
      }
    }

    // ---- S^T = K Q^T for both subtiles, K-frags shared; C starts at mask bias ----
    f32x16 sA0 = ini0, sA1 = ini1, sB0 = ini0, sB1 = ini1;
    __builtin_amdgcn_s_setprio(1);
#pragma unroll
    for (int kc = 0; kc < 4; kc++) {
      f16x8 k0 = *(const f16x8*)&ks[idxA[kc]];
      f16x8 k1 = *(const f16x8*)&ks[idxB[kc]];
      sA0 = __builtin_amdgcn_mfma_f32_32x32x16_f16(k0, aqA[kc], sA0, 0, 0, 0);
      sA1 = __builtin_amdgcn_mfma_f32_32x32x16_f16(k1, aqA[kc], sA1, 0, 0, 0);
      sB0 = __builtin_amdgcn_mfma_f32_32x32x16_f16(k0, aqB[kc], sB0, 0, 0, 0);
      sB1 = __builtin_amdgcn_mfma_f32_32x32x16_f16(k1, aqB[kc], sB1, 0, 0, 0);
    }
    __builtin_amdgcn_s_setprio(0);

    // ---- fused p=exp2(S+bias) -> l += p (f32 adds) -> f16 pack -> permlane -> PV ----
#pragma unroll
    for (int g = 0; g < 4; g++) {
      const f32x16& srcA = (g < 2) ? sA0 : sA1;
      const f32x16& srcB = (g < 2) ? sB0 : sB1;
      const int o = (g & 1) * 8;
      u32 wa[4], wb[4];
#pragma unroll
      for (int s = 0; s < 4; s++) {
        float ea0 = __builtin_amdgcn_exp2f(srcA[o + 2 * s]);
        float ea1 = __builtin_amdgcn_exp2f(srcA[o + 2 * s + 1]);
        float eb0 = __builtin_amdgcn_exp2f(srcB[o + 2 * s]);
        float eb1 = __builtin_amdgcn_exp2f(srcB[o + 2 * s + 1]);
        wa[s] = __builtin_bit_cast(u32, __builtin_amdgcn_cvt_pkrtz(ea0, ea1));
        wb[s] = __builtin_bit_cast(u32, __builtin_amdgcn_cvt_pkrtz(eb0, eb1));
        lA += ea0 + ea1;
        lB += eb0 + eb1;
      }
      u32x2 rA0 = __builtin_amdgcn_permlane32_swap(wa[0], wa[2], false, false);
      u32x2 rA1 = __builtin_amdgcn_permlane32_swap(wa[1], wa[3], false, false);
      u32x2 rB0 = __builtin_amdgcn_permlane32_swap(wb[0], wb[2], false, false);
      u32x2 rB1 = __builtin_amdgcn_permlane32_swap(wb[1], wb[3], false, false);
      uint4 f4A; f4A.x = rA0[0]; f4A.y = rA1[0]; f4A.z = rA0[1]; f4A.w = rA1[1];
      uint4 f4B; f4B.x = rB0[0]; f4B.y = rB1[0]; f4B.z = rB0[1]; f4B.w = rB1[1];
      f16x8 fA = __builtin_bit_cast(f16x8, f4A);
      f16x8 fB = __builtin_bit_cast(f16x8, f4B);
      f16x8 bv0 = *(const f16x8*)&vs[idxA[g]];
      f16x8 bv1 = *(const f16x8*)&vs[idxB[g]];
      __builtin_amdgcn_s_setprio(1);
      accO0A = __builtin_amdgcn_mfma_f32_32x32x16_f16(fA, bv0, accO0A, 0, 0, 0);
      accO1A = __builtin_amdgcn_mfma_f32_32x32x16_f16(fA, bv1, accO1A, 0, 0, 0);
      accO0B = __builtin_amdgcn_mfma_f32_32x32x16_f16(fB, bv0, accO0B, 0, 0, 0);
      accO1B = __builtin_amdgcn_mfma_f32_32x32x16_f16(fB, bv1, accO1B, 0, 0, 0);
      __builtin_amdgcn_s_setprio(0);
    }
  }

  // ---- epilogue ----
  // merge partner t-half: lanes l and l^32 hold complementary t-subsets of q=l31.
  // __shfl_xor (NOT permlane32_swap(x,x) -- see header note / R3+R5 post-mortem).
  float lAf = lA + __shfl_xor(lA, 32, 64);
  float lBf = lB + __shfl_xor(lB, 32, 64);
  float invA = (lAf > 0.f) ? 1.f / lAf : 0.f;   // lane holds 1/l for q = l31
  float invB = (lBf > 0.f) ? 1.f / lBf : 0.f;
#pragma unroll
  for (int r = 0; r < 16; r++) {
    int qr = (r & 3) + 8 * (r >> 2) + 4 * hi;
    float iA = __builtin_bit_cast(float,
        (u32)__builtin_amdgcn_ds_bpermute(qr << 2, (int)__builtin_bit_cast(u32, invA)));
    float iB = __builtin_bit_cast(float,
        (u32)__builtin_amdgcn_ds_bpermute(qr << 2, (int)__builtin_bit_cast(u32, invB)));
    float* opA = out + ((size_t)(b * S_LEN + q0 + qr) * DMODEL) + h * DHEAD;
    float* opB = out + ((size_t)(b * S_LEN + q0 + 32 + qr) * DMODEL) + h * DHEAD;
    opA[l31] = accO0A[r] * iA;
    opA[32 + l31] = accO1A[r] * iA;
    opB[l31] = accO0B[r] * iB;
    opB[32 + l31] = accO1B[r] * iB;
  }
}

extern "C" void kernel_launch(void* const* d_in, const int* in_sizes, int n_in,
                              void* d_out, int out_size, void* d_ws, size_t ws_size,
                              hipStream_t stream) {
  const float* x    = (const float*)d_in[0];
  const float* mask = (const float*)d_in[1];
  const float* Wq   = (const float*)d_in[2];
  const float* bq   = (const float*)d_in[3];
  const float* Wk   = (const float*)d_in[4];
  const float* bk   = (const float*)d_in[5];
  const float* Wv   = (const float*)d_in[6];
  const float* bv   = (const float*)d_in[7];
  float* out = (float*)d_out;

  u16* xb = (u16*)d_ws;                         // [8192][1024] f16
  u16* wt = xb + (size_t)8192 * 1024;           // [3072][1024] f16 (W^T, q|k|v)
  u16* Qb = wt + (size_t)3072 * 1024;           // [4][16][2048][64]
  u16* Kb = Qb + (size_t)8388608;               // [4][16][2048][64]
  u16* Vb = Kb + (size_t)8388608;               // [4][16][64][2048] (mask-zeroed)

  cvt_x<<<2048, 256, 0, stream>>>(x, xb, (8192 * 1024) / 4);
  trans_w<<<dim3(32, 32), 256, 0, stream>>>(Wq, wt);
  trans_w<<<dim3(32, 32), 256, 0, stream>>>(Wk, wt + (size_t)1024 * 1024);
  trans_w<<<dim3(32, 32), 256, 0, stream>>>(Wv, wt + (size_t)2 * 1024 * 1024);
  qkv_gemm<<<dim3(64, 24), 256, 0, stream>>>(xb, wt, bq, bk, bv, mask, Qb, Kb, Vb);
  attn<<<512, 256, 0, stream>>>(Qb, Kb, Vb, mask, out);
}